// Round 12
// baseline (374.938 us; speedup 1.0000x reference)
//
#include <hip/hip_runtime.h>
#include <hip/hip_bf16.h>
#include <math.h>

typedef __bf16 bf16x8 __attribute__((ext_vector_type(8)));
typedef __bf16 bf16x4 __attribute__((ext_vector_type(4)));
typedef float  f32x4  __attribute__((ext_vector_type(4)));
typedef float  f32x16 __attribute__((ext_vector_type(16)));
typedef short  s16x8  __attribute__((ext_vector_type(8)));

#define N_TOK  4096
#define DMODEL 1024
#define NHEAD  4
#define DHEAD  256

__device__ __forceinline__ f32x4 mfma16x16(bf16x8 a, bf16x8 b, f32x4 c) {
    return __builtin_amdgcn_mfma_f32_16x16x32_bf16(a, b, c, 0, 0, 0);
}
__device__ __forceinline__ f32x16 mfma32(bf16x8 a, bf16x8 b, f32x16 c) {
    return __builtin_amdgcn_mfma_f32_32x32x16_bf16(a, b, c, 0, 0, 0);
}
// pack 2 f32 -> u32 of 2 bf16 (lo in [15:0]); no builtin on gfx950 (m240)
__device__ __forceinline__ unsigned cvtpk(float lo, float hi) {
    unsigned r;
    asm("v_cvt_pk_bf16_f32 %0, %1, %2" : "=v"(r) : "v"(lo), "v"(hi));
    return r;
}

// async global->LDS, 16B per lane; LDS dest = wave-uniform base + lane*16
__device__ __forceinline__ void gload_lds16(const void* gsrc, void* ldst) {
    __builtin_amdgcn_global_load_lds(
        (const __attribute__((address_space(1))) void*)gsrc,
        (__attribute__((address_space(3))) void*)ldst, 16, 0, 0);
}

// ---- batched fp32 -> bf16 convert (q,k,v), 8 elem/thread
struct CvtArgs { const float* src[3]; __bf16* dst[3]; };
__global__ __launch_bounds__(256)
void cvt_bf16_kernel(CvtArgs a)
{
    const float* in = a.src[blockIdx.y];
    __bf16* out = a.dst[blockIdx.y];
    size_t i8 = ((size_t)blockIdx.x * 256 + threadIdx.x) * 8;
    f32x4 t0 = *(const f32x4*)(in + i8);
    f32x4 t1 = *(const f32x4*)(in + i8 + 4);
    bf16x8 b;
    #pragma unroll
    for (int j = 0; j < 4; ++j) { b[j] = (__bf16)t0[j]; b[j + 4] = (__bf16)t1[j]; }
    *(bf16x8*)(out + i8) = b;
}

// ---- weight transpose+convert: in [1024][C] fp32 -> out [C][1024] bf16
__device__ __forceinline__ void transposew_body(const float* __restrict__ in,
                                                __bf16* __restrict__ out, int C)
{
    __shared__ __align__(16) __bf16 tile[64 * 72];
    const int tid = threadIdx.x;
    const int r0 = blockIdx.x * 64;
    const int c0 = blockIdx.y * 64;
    if (c0 >= C) return;
    #pragma unroll
    for (int it = 0; it < 4; ++it) {
        int i = tid + it * 256;
        int row = i >> 4, c4 = i & 15;
        f32x4 v = *(const f32x4*)(in + (size_t)(r0 + row) * C + c0 + c4 * 4);
        #pragma unroll
        for (int j = 0; j < 4; ++j)
            tile[(c4 * 4 + j) * 72 + row] = (__bf16)v[j];
    }
    __syncthreads();
    #pragma unroll
    for (int it = 0; it < 2; ++it) {
        int i = tid + it * 256;
        int col = i >> 3, ch = i & 7;
        s16x8 v = *(const s16x8*)(&tile[col * 72 + ch * 8]);
        *(s16x8*)((short*)out + (size_t)(c0 + col) * 1024 + r0 + ch * 8) = v;
    }
}

__global__ __launch_bounds__(256)
void transposew_kernel(const float* __restrict__ in, __bf16* __restrict__ out, int C)
{
    transposew_body(in, out, C);
}

struct TWArgs { const float* src[4]; __bf16* dst[4]; int C[4]; };
__global__ __launch_bounds__(256)
void transposew_batch_kernel(TWArgs a)
{
    int z = blockIdx.z;
    transposew_body(a.src[z], a.dst[z], a.C[z]);
}

// ---- FUSED bt-GEMM batch (R9-proven): 128x128 tile, 832 blocks -> 2/CU
struct GemmDesc {
    const __bf16* A; const __bf16* B; const float* bias; __bf16* C;
    int lda, ldb, ldc, gx, nblocks, relu, biasrow; float scale;
};
struct FusedArgs { GemmDesc d[4]; };

__global__ __launch_bounds__(256, 2)
void gemm_fused(FusedArgs fa)
{
    __shared__ __align__(16) short As[2][128 * 64];
    __shared__ __align__(16) short Bs[2][128 * 64];

    int b = blockIdx.x, z = 0;
    while (b >= fa.d[z].nblocks) { b -= fa.d[z].nblocks; ++z; }
    const GemmDesc D = fa.d[z];
    const int m0 = (b % D.gx) * 128;
    const int n0 = (b / D.gx) * 128;

    const int tid  = threadIdx.x;
    const int lane = tid & 63;
    const int wv   = tid >> 6;
    const int c16  = lane & 15;
    const int quad = lane >> 4;
    const int swz  = c16 & 7;
    const int wr   = wv >> 1;
    const int wc   = wv & 1;

    f32x4 acc[4][4];
    #pragma unroll
    for (int i = 0; i < 4; ++i)
        #pragma unroll
        for (int j = 0; j < 4; ++j)
            acc[i][j] = (f32x4){0.f, 0.f, 0.f, 0.f};

    const int sRow = lane >> 3;
    const int sCh  = (lane & 7) ^ (sRow & 7);

    auto issue = [&](short* Abuf, short* Bbuf, int k0) {
        #pragma unroll
        for (int g = 0; g < 4; ++g) {
            int row = 32 * wv + 8 * g + sRow;
            const char* src = (const char*)(D.A + (size_t)(m0 + row) * D.lda + k0) + sCh * 16;
            gload_lds16(src, (char*)Abuf + (32 * wv + 8 * g) * 128);
        }
        #pragma unroll
        for (int g = 0; g < 4; ++g) {
            int row = 32 * wv + 8 * g + sRow;
            const char* src = (const char*)(D.B + (size_t)(n0 + row) * D.ldb + k0) + sCh * 16;
            gload_lds16(src, (char*)Bbuf + (32 * wv + 8 * g) * 128);
        }
    };
    auto compute = [&](const short* Abuf, const short* Bbuf) {
        __builtin_amdgcn_s_setprio(1);
        #pragma unroll
        for (int ks = 0; ks < 2; ++ks) {
            bf16x8 af[4], bfr[4];
            int slot = ((ks * 4 + quad) ^ swz) * 16;
            #pragma unroll
            for (int t = 0; t < 4; ++t)
                af[t] = *(const bf16x8*)((const char*)Abuf + (wr * 64 + t * 16 + c16) * 128 + slot);
            #pragma unroll
            for (int t = 0; t < 4; ++t)
                bfr[t] = *(const bf16x8*)((const char*)Bbuf + (wc * 64 + t * 16 + c16) * 128 + slot);
            #pragma unroll
            for (int tm = 0; tm < 4; ++tm)
                #pragma unroll
                for (int tn = 0; tn < 4; ++tn)
                    acc[tm][tn] = mfma16x16(af[tm], bfr[tn], acc[tm][tn]);
        }
        __builtin_amdgcn_s_setprio(0);
    };

    issue(As[0], Bs[0], 0);
    __syncthreads();

    #pragma unroll 1
    for (int t = 0; t < 16; t += 2) {
        if (t + 1 < 16) issue(As[1], Bs[1], (t + 1) << 6);
        compute(As[0], Bs[0]);
        __syncthreads();
        if (t + 2 < 16) issue(As[0], Bs[0], (t + 2) << 6);
        compute(As[1], Bs[1]);
        __syncthreads();
    }

    #pragma unroll
    for (int tm = 0; tm < 4; ++tm) {
        #pragma unroll
        for (int rr = 0; rr < 4; ++rr) {
            int row = m0 + wr * 64 + tm * 16 + quad * 4 + rr;
            float rbv = D.biasrow ? D.bias[row] : 0.0f;
            #pragma unroll
            for (int tn = 0; tn < 4; ++tn) {
                int col = n0 + wc * 64 + tn * 16 + c16;
                float bb = D.biasrow ? rbv : D.bias[col];
                float val = (acc[tm][tn][rr] + bb) * D.scale;
                if (D.relu) val = fmaxf(val, 0.0f);
                D.C[(size_t)row * D.ldc + col] = (__bf16)val;
            }
        }
    }
}

// ---- bt-GEMM 128x64 tile (R5-proven; 512 blocks = 2/CU) for out-projection
template<typename OutT, bool BIASROW>
__global__ __launch_bounds__(256, 2)
void gemm_bt64(const __bf16* __restrict__ A, int lda,
               const __bf16* __restrict__ B, int ldb,
               const float* __restrict__ bias,
               OutT* __restrict__ C, int ldc,
               float scale, int relu, const float* __restrict__ rowmask, int K)
{
    __shared__ __align__(16) short As[2][128 * 64];
    __shared__ __align__(16) short Bs[2][64 * 64];
    const int tid  = threadIdx.x;
    const int lane = tid & 63;
    const int wv   = tid >> 6;
    const int c16  = lane & 15;
    const int quad = lane >> 4;
    const int swz  = c16 & 7;
    const int wr   = wv >> 1;
    const int wc   = wv & 1;
    const int m0 = blockIdx.x * 128;
    const int n0 = blockIdx.y * 64;

    f32x4 acc[4][2];
    #pragma unroll
    for (int i = 0; i < 4; ++i)
        #pragma unroll
        for (int j = 0; j < 2; ++j)
            acc[i][j] = (f32x4){0.f, 0.f, 0.f, 0.f};

    const int sRow = lane >> 3;
    const int sCh  = (lane & 7) ^ (sRow & 7);

    auto issue = [&](short* Abuf, short* Bbuf, int k0) {
        #pragma unroll
        for (int g = 0; g < 4; ++g) {
            int row = 32 * wv + 8 * g + sRow;
            const char* src = (const char*)(A + (size_t)(m0 + row) * lda + k0) + sCh * 16;
            gload_lds16(src, (char*)Abuf + (32 * wv + 8 * g) * 128);
        }
        #pragma unroll
        for (int g = 0; g < 2; ++g) {
            int row = 16 * wv + 8 * g + sRow;
            const char* src = (const char*)(B + (size_t)(n0 + row) * ldb + k0) + sCh * 16;
            gload_lds16(src, (char*)Bbuf + (16 * wv + 8 * g) * 128);
        }
    };
    auto compute = [&](const short* Abuf, const short* Bbuf) {
        __builtin_amdgcn_s_setprio(1);
        #pragma unroll
        for (int ks = 0; ks < 2; ++ks) {
            bf16x8 af[4], bfr[2];
            int slot = ((ks * 4 + quad) ^ swz) * 16;
            #pragma unroll
            for (int t = 0; t < 4; ++t)
                af[t] = *(const bf16x8*)((const char*)Abuf + (wr * 64 + t * 16 + c16) * 128 + slot);
            #pragma unroll
            for (int t = 0; t < 2; ++t)
                bfr[t] = *(const bf16x8*)((const char*)Bbuf + (wc * 32 + t * 16 + c16) * 128 + slot);
            #pragma unroll
            for (int tm = 0; tm < 4; ++tm)
                #pragma unroll
                for (int tn = 0; tn < 2; ++tn)
                    acc[tm][tn] = mfma16x16(af[tm], bfr[tn], acc[tm][tn]);
        }
        __builtin_amdgcn_s_setprio(0);
    };

    const int nt = K >> 6;
    issue(As[0], Bs[0], 0);
    __syncthreads();

    #pragma unroll 1
    for (int t = 0; t < nt; t += 2) {
        if (t + 1 < nt) issue(As[1], Bs[1], (t + 1) << 6);
        compute(As[0], Bs[0]);
        __syncthreads();
        if (t + 1 < nt) {
            if (t + 2 < nt) issue(As[0], Bs[0], (t + 2) << 6);
            compute(As[1], Bs[1]);
            __syncthreads();
        }
    }

    #pragma unroll
    for (int tm = 0; tm < 4; ++tm) {
        #pragma unroll
        for (int rr = 0; rr < 4; ++rr) {
            int row = m0 + wr * 64 + tm * 16 + quad * 4 + rr;
            float mk = rowmask ? rowmask[row] : 1.0f;
            float rbv = BIASROW ? bias[row] : 0.0f;
            #pragma unroll
            for (int tn = 0; tn < 2; ++tn) {
                int col = n0 + wc * 32 + tn * 16 + c16;
                float b = BIASROW ? rbv : bias[col];
                float val = (acc[tm][tn][rr] + b) * scale;
                if (relu) val = fmaxf(val, 0.0f);
                val *= mk;
                C[(size_t)row * ldc + col] = (OutT)val;
            }
        }
    }
}

// ---- scores -> mask (unchanged)
__global__ void score_mask_kernel(const __bf16* __restrict__ h,
                                  const float* __restrict__ w2,
                                  const float* __restrict__ b2,
                                  float* __restrict__ maskf)
{
    int lane = threadIdx.x & 63;
    int tok  = blockIdx.x * 4 + (threadIdx.x >> 6);
    const __bf16* hr = h + (size_t)tok * 256;
    float s = 0.f;
    #pragma unroll
    for (int j = 0; j < 4; ++j) {
        int c = j * 64 + lane;
        s += (float)hr[c] * w2[c];
    }
    #pragma unroll
    for (int o = 1; o < 64; o <<= 1) s += __shfl_xor(s, o);
    if (lane == 0) {
        float x = s + b2[0];
        maskf[tok] = (x > -1.7346010553881064f) ? 1.0f : 0.0f;
    }
}

// ---- flash attention, 32x32 MFMA, swapped QK^T, in-register softmax.
// R7 kernel VERBATIM except __launch_bounds__(512, 1): R7's (512,2) capped
// VGPR at 128 and spilled 59 MB; at (512,1) the 8-wave block gets the full
// 256-reg budget (o[8]x16=128 acc + qf[16]=64 + temps ~ 245).
// QBLK=256 (8 waves x 32 q-rows), KVBLK=64, K/V dbuf via gload_lds + XOR swz.
// Grid 256 = (16 qb, 4 head, 4 ksp), XCD-clustered. Unnormalized partials.
__global__ __launch_bounds__(512, 1)
void attn_kernel(const __bf16* __restrict__ qp, const __bf16* __restrict__ kp,
                 const __bf16* __restrict__ vpT, const float* __restrict__ maskf,
                 __bf16* __restrict__ O0, __bf16* __restrict__ O1,
                 __bf16* __restrict__ O2, __bf16* __restrict__ O3,
                 float* __restrict__ lbuf)
{
    __shared__ __align__(16) short Ks[2][64 * 256];    // 64 KB
    __shared__ __align__(16) short Vs[2][256 * 64];    // 64 KB

    const int tid  = threadIdx.x;
    const int lane = tid & 63;
    const int wv   = tid >> 6;       // 0..7
    const int l31  = lane & 31;
    const int hi   = lane >> 5;      // 0/1
    const int swz  = lane & 7;

    const int d    = blockIdx.x;     // 0..255
    const int g    = d & 7;          // XCD
    const int t    = d >> 3;         // 0..31
    const int head = g >> 1;
    const int ksp  = (g & 1) * 2 + (t >> 4);
    const int qb   = t & 15;
    const int kbase = ksp * 1024;
    const int q0w  = qb * 256 + wv * 32;
    __bf16* Ob = (ksp == 0) ? O0 : (ksp == 1) ? O1 : (ksp == 2) ? O2 : O3;

    // Q fragments, B-operand layout: col = q = lane&31, k = hi*8+j; 16 k-steps
    bf16x8 qf[16];
    #pragma unroll
    for (int c = 0; c < 16; ++c)
        qf[c] = *(const bf16x8*)(qp + (size_t)(q0w + l31) * DMODEL + head * DHEAD + c * 16 + hi * 8);

    f32x16 o[8];
    #pragma unroll
    for (int i = 0; i < 8; ++i)
        #pragma unroll
        for (int r = 0; r < 16; ++r) o[i][r] = 0.f;
    float ps0 = 0.f, ps1 = 0.f, ps2 = 0.f, ps3 = 0.f;

    const int kRow0 = wv * 8 + (lane >> 5);
    const int kCh   = lane & 31;
    const int vRow0 = wv * 32 + (lane >> 3);
    const int vCh   = (lane & 7) ^ ((lane >> 3) & 7);

    auto issue = [&](int buf, int n0) {
        #pragma unroll
        for (int gg = 0; gg < 4; ++gg) {
            int key = kRow0 + gg * 2;
            int c   = kCh ^ (key & 7);
            const char* src = (const char*)(kp + (size_t)(n0 + key) * DMODEL + head * DHEAD) + c * 16;
            gload_lds16(src, (char*)Ks[buf] + (wv * 8 + gg * 2) * 512);
        }
        #pragma unroll
        for (int gg = 0; gg < 4; ++gg) {
            int row = vRow0 + gg * 8;
            const char* src = (const char*)(vpT + (size_t)(head * DHEAD + row) * N_TOK + n0) + vCh * 16;
            gload_lds16(src, (char*)Vs[buf] + (wv * 32 + gg * 8) * 128);
        }
    };

    issue(0, kbase);
    __syncthreads();
    int cur = 0;

    #pragma unroll 1
    for (int n0 = kbase; n0 < kbase + 1024; n0 += 64) {
        if (n0 + 64 < kbase + 1024) issue(cur ^ 1, n0 + 64);
        const short* Kb = Ks[cur];
        const short* Vb = Vs[cur];

        #pragma unroll
        for (int kb = 0; kb < 2; ++kb) {
            // S' = K . Q^T : col = q = lane&31, row(reg r) = (r&3)+8*(r>>2)+4*hi
            f32x16 s;
            #pragma unroll
            for (int r = 0; r < 16; ++r) s[r] = 0.f;
            __builtin_amdgcn_s_setprio(1);
            #pragma unroll
            for (int c = 0; c < 16; ++c) {
                bf16x8 kf = *(const bf16x8*)((const char*)Kb + (kb * 32 + l31) * 512 + (((c * 2 + hi) ^ swz) << 4));
                s = mfma32(kf, qf[c], s);
            }
            __builtin_amdgcn_s_setprio(0);

            // two 16-key halves: exp+mask -> pack -> 8 PV MFMAs (diet: 8p live)
            #pragma unroll
            for (int half = 0; half < 2; ++half) {
                float p[8];
                #pragma unroll
                for (int gq = 0; gq < 2; ++gq) {
                    f32x4 mv = *(const f32x4*)(maskf + n0 + kb * 32 + (half * 2 + gq) * 8 + hi * 4);
                    #pragma unroll
                    for (int j = 0; j < 4; ++j) {
                        float pv = __expf(s[(half * 2 + gq) * 4 + j]) * mv[j];
                        p[gq * 4 + j] = pv;
                        if (j == 0) ps0 += pv; else if (j == 1) ps1 += pv;
                        else if (j == 2) ps2 += pv; else ps3 += pv;
                    }
                }
                unsigned A = cvtpk(p[0], p[1]), B = cvtpk(p[2], p[3]);
                unsigned C = cvtpk(p[4], p[5]), D = cvtpk(p[6], p[7]);
                unsigned y0 = (unsigned)__shfl_xor((int)(hi ? A : C), 32);
                unsigned y1 = (unsigned)__shfl_xor((int)(hi ? B : D), 32);
                union { unsigned u[4]; bf16x8 v; } pa;
                pa.u[0] = hi ? y0 : A;  pa.u[1] = hi ? y1 : B;
                pa.u[2] = hi ? C  : y0; pa.u[3] = hi ? D  : y1;
                int chunk = (kb * 2 + half) * 2 + hi;
                __builtin_amdgcn_s_setprio(1);
                #pragma unroll
                for (int dhb = 0; dhb < 8; ++dhb) {
                    bf16x8 vf = *(const bf16x8*)((const char*)Vb + (dhb * 32 + l31) * 128 + ((chunk ^ swz) << 4));
                    o[dhb] = mfma32(pa.v, vf, o[dhb]);
                }
                __builtin_amdgcn_s_setprio(0);
            }
        }
        __syncthreads();   // drains next-tile gloads (overlapped with compute)
        cur ^= 1;
    }

    // denominator: own half + partner half
    float psum = (ps0 + ps1) + (ps2 + ps3);
    float tot = psum + __shfl_xor(psum, 32);
    if (lane < 32)
        lbuf[(size_t)(ksp * NHEAD + head) * N_TOK + q0w + l31] = tot;

    // epilogue: o -> per-wave 16KB LDS region (K/V dead after last barrier),
    // then coalesced bf16x8 stores. Same-wave only: lgkmcnt, no s_barrier.
    short* Osm = (wv < 4) ? ((short*)Ks + wv * 8192) : ((short*)Vs + (wv - 4) * 8192);
    #pragma unroll
    for (int dhb = 0; dhb < 8; ++dhb)
        #pragma unroll
        for (int r = 0; r < 16; ++r) {
            int qrow = (r & 3) + 8 * (r >> 2) + 4 * hi;
            *(__bf16*)&Osm[qrow * 256 + dhb * 32 + l31] = (__bf16)o[dhb][r];
        }
    __builtin_amdgcn_s_waitcnt(0xc07f);  // lgkmcnt(0)
    #pragma unroll
    for (int j = 0; j < 16; ++j) {
        int row = j * 2 + hi;
        bf16x8 tv = *(const bf16x8*)&Osm[row * 256 + l31 * 8];
        *(bf16x8*)(Ob + (size_t)(q0w + row) * DMODEL + head * DHEAD + l31 * 8) = tv;
    }
}

// ---- combine: ctx = (O0+O1+O2+O3) / (l0+l1+l2+l3)  (exact, shared m=0)
__global__ void combine_kernel(const __bf16* __restrict__ O0,
                               const __bf16* __restrict__ O1,
                               const __bf16* __restrict__ O2,
                               const __bf16* __restrict__ O3,
                               const float* __restrict__ lbuf,
                               __bf16* __restrict__ out)
{
    int idx  = blockIdx.x * 256 + threadIdx.x;
    int tok  = idx >> 7;
    int g    = idx & 127;
    int head = g >> 5;
    float l0 = lbuf[(size_t)(0 * NHEAD + head) * N_TOK + tok];
    float l1 = lbuf[(size_t)(1 * NHEAD + head) * N_TOK + tok];
    float l2 = lbuf[(size_t)(2 * NHEAD + head) * N_TOK + tok];
    float l3 = lbuf[(size_t)(3 * NHEAD + head) * N_TOK + tok];
    float inv = 1.0f / (l0 + l1 + l2 + l3);
    size_t off = (size_t)tok * DMODEL + g * 8;
    bf16x8 a = *(const bf16x8*)(O0 + off);
    bf16x8 b = *(const bf16x8*)(O1 + off);
    bf16x8 c = *(const bf16x8*)(O2 + off);
    bf16x8 dd = *(const bf16x8*)(O3 + off);
    bf16x8 z;
    #pragma unroll
    for (int j = 0; j < 8; ++j)
        z[j] = (__bf16)((((float)a[j] + (float)b[j]) + ((float)c[j] + (float)dd[j])) * inv);
    *(bf16x8*)(out + off) = z;
}

extern "C" void kernel_launch(void* const* d_in, const int* in_sizes, int n_in,
                              void* d_out, int out_size, void* d_ws, size_t ws_size,
                              hipStream_t stream)
{
    (void)in_sizes; (void)n_in; (void)out_size;
    const float* q  = (const float*)d_in[0];
    const float* k  = (const float*)d_in[1];
    const float* v  = (const float*)d_in[2];
    const float* w1 = (const float*)d_in[3];
    const float* b1 = (const float*)d_in[4];
    const float* w2 = (const float*)d_in[5];
    const float* b2 = (const float*)d_in[6];
    const float* wq = (const float*)d_in[7];
    const float* bq = (const float*)d_in[8];
    const float* wk = (const float*)d_in[9];
    const float* bk = (const float*)d_in[10];
    const float* wvw = (const float*)d_in[11];
    const float* bv = (const float*)d_in[12];
    const float* wo = (const float*)d_in[13];
    const float* bo = (const float*)d_in[14];

    if (ws_size < 35667968u + 8388608u + 131072u) return;  // proven floor (R5)

    char* ws = (char*)d_ws;
    float*  maskf = (float*)ws;                       // 16 KB
    __bf16* hbuf  = (__bf16*)(ws + 16384);            // 2 MB region: h -> lbuf -> woT
    float*  lbuf  = (float*)(ws + 16384);             // [4][4][4096] f32 = 256 KB
    __bf16* qp    = (__bf16*)(ws + 16384 + 2097152);  // 8 MB each
    __bf16* kpb   = qp  + 4194304;
    __bf16* vpT   = kpb + 4194304;                    // [1024][4096] via swapped V-gemm
    __bf16* ctx   = vpT + 4194304;                    // O0; kbf scratch before attn
    __bf16* O1    = (__bf16*)(ws + 35667968u);        // 8 MB; qbf scratch before attn

    // d_out (16 MB fp32) scratch, dead before final GEMM overwrites it:
    // wqT@0 | wkT@2M | wvT@4M | w1T@6M | vbf@6.5M..14.5M ; then O2@0, O3@8M
    __bf16* wqT = (__bf16*)d_out;
    __bf16* wkT = wqT + 1048576;
    __bf16* wvT = wkT + 1048576;
    __bf16* w1T = wvT + 1048576;
    __bf16* vbf = (__bf16*)((char*)d_out + 6815744u);
    __bf16* O2  = (__bf16*)d_out;                     // after fused projections
    __bf16* O3  = (__bf16*)((char*)d_out + 8388608u);
    __bf16* woT = hbuf;                               // written AFTER combine
    __bf16* qbf = O1;                                 // dead until attn writes O1
    __bf16* kbf = ctx;                                // dead until attn writes O0

    // 0) q,k,v -> bf16
    CvtArgs ca;
    ca.src[0] = q;  ca.dst[0] = qbf;
    ca.src[1] = k;  ca.dst[1] = kbf;
    ca.src[2] = v;  ca.dst[2] = vbf;
    cvt_bf16_kernel<<<dim3(2048, 3), 256, 0, stream>>>(ca);

    // 1) transpose w1,wq,wk,wv (one launch)
    TWArgs ta;
    ta.src[0] = w1;  ta.dst[0] = w1T;  ta.C[0] = 256;
    ta.src[1] = wq;  ta.dst[1] = wqT;  ta.C[1] = 1024;
    ta.src[2] = wk;  ta.dst[2] = wkT;  ta.C[2] = 1024;
    ta.src[3] = wvw; ta.dst[3] = wvT;  ta.C[3] = 1024;
    transposew_batch_kernel<<<dim3(16, 16, 4), 256, 0, stream>>>(ta);

    // 2) FUSED: h = relu(q@w1+b1) | qp = (q@wq)/16 | kp = k@wk | vpT = (v@wv)^T
    FusedArgs fa;
    fa.d[0] = { qbf, w1T, b1, hbuf, 1024, 1024,  256, 32,  64, 1, 0, 1.0f };
    fa.d[1] = { qbf, wqT, bq, qp,   1024, 1024, 1024, 32, 256, 0, 0, 0.0625f };
    fa.d[2] = { kbf, wkT, bk, kpb,  1024, 1024, 1024, 32, 256, 0, 0, 1.0f };
    fa.d[3] = { wvT, vbf, bv, vpT,  1024, 1024, 4096,  8, 256, 0, 1, 1.0f };
    gemm_fused<<<dim3(832), 256, 0, stream>>>(fa);

    // 3) mask (h dead after; lbuf reuses its region)
    score_mask_kernel<<<1024, 256, 0, stream>>>(hbuf, w2, b2, maskf);

    // 4) attention: 256 blocks x 512 thr, 4 k-splits, unnormalized partials
    attn_kernel<<<dim3(256), 512, 0, stream>>>(qp, kpb, vpT, maskf, ctx, O1, O2, O3, lbuf);
    combine_kernel<<<2048, 256, 0, stream>>>(ctx, O1, O2, O3, lbuf, ctx);

    // 5) wo^T into hbuf (lbuf dead after combine), then out-projection
    transposew_kernel<<<dim3(16, 16), 256, 0, stream>>>(wo, woT, 1024);
    gemm_bt64<float, false><<<dim3(32, 16), 256, 0, stream>>>(
        ctx, 1024, woT, 1024, bo, (float*)d_out, 1024, 1.0f, 0, maskf, 1024);
}

// Round 13
// 306.114 us; speedup vs baseline: 1.2248x; 1.2248x over previous
//
#include <hip/hip_runtime.h>
#include <hip/hip_bf16.h>
#include <math.h>

typedef __bf16 bf16x8 __attribute__((ext_vector_type(8)));
typedef __bf16 bf16x4 __attribute__((ext_vector_type(4)));
typedef float  f32x4  __attribute__((ext_vector_type(4)));
typedef short  s16x8  __attribute__((ext_vector_type(8)));

#define N_TOK  4096
#define DMODEL 1024
#define NHEAD  4
#define DHEAD  256

__device__ __forceinline__ f32x4 mfma16x16(bf16x8 a, bf16x8 b, f32x4 c) {
    return __builtin_amdgcn_mfma_f32_16x16x32_bf16(a, b, c, 0, 0, 0);
}

// async global->LDS, 16B per lane; LDS dest = wave-uniform base + lane*16
__device__ __forceinline__ void gload_lds16(const void* gsrc, void* ldst) {
    __builtin_amdgcn_global_load_lds(
        (const __attribute__((address_space(1))) void*)gsrc,
        (__attribute__((address_space(3))) void*)ldst, 16, 0, 0);
}

// ---- batched fp32 -> bf16 convert (q,k,v), 8 elem/thread
struct CvtArgs { const float* src[3]; __bf16* dst[3]; };
__global__ __launch_bounds__(256)
void cvt_bf16_kernel(CvtArgs a)
{
    const float* in = a.src[blockIdx.y];
    __bf16* out = a.dst[blockIdx.y];
    size_t i8 = ((size_t)blockIdx.x * 256 + threadIdx.x) * 8;
    f32x4 t0 = *(const f32x4*)(in + i8);
    f32x4 t1 = *(const f32x4*)(in + i8 + 4);
    bf16x8 b;
    #pragma unroll
    for (int j = 0; j < 4; ++j) { b[j] = (__bf16)t0[j]; b[j + 4] = (__bf16)t1[j]; }
    *(bf16x8*)(out + i8) = b;
}

// ---- weight transpose+convert: in [1024][C] fp32 -> out [C][1024] bf16
__device__ __forceinline__ void transposew_body(const float* __restrict__ in,
                                                __bf16* __restrict__ out, int C)
{
    __shared__ __align__(16) __bf16 tile[64 * 72];
    const int tid = threadIdx.x;
    const int r0 = blockIdx.x * 64;
    const int c0 = blockIdx.y * 64;
    if (c0 >= C) return;
    #pragma unroll
    for (int it = 0; it < 4; ++it) {
        int i = tid + it * 256;
        int row = i >> 4, c4 = i & 15;
        f32x4 v = *(const f32x4*)(in + (size_t)(r0 + row) * C + c0 + c4 * 4);
        #pragma unroll
        for (int j = 0; j < 4; ++j)
            tile[(c4 * 4 + j) * 72 + row] = (__bf16)v[j];
    }
    __syncthreads();
    #pragma unroll
    for (int it = 0; it < 2; ++it) {
        int i = tid + it * 256;
        int col = i >> 3, ch = i & 7;
        s16x8 v = *(const s16x8*)(&tile[col * 72 + ch * 8]);
        *(s16x8*)((short*)out + (size_t)(c0 + col) * 1024 + r0 + ch * 8) = v;
    }
}

__global__ __launch_bounds__(256)
void transposew_kernel(const float* __restrict__ in, __bf16* __restrict__ out, int C)
{
    transposew_body(in, out, C);
}

struct TWArgs { const float* src[4]; __bf16* dst[4]; int C[4]; };
__global__ __launch_bounds__(256)
void transposew_batch_kernel(TWArgs a)
{
    int z = blockIdx.z;
    transposew_body(a.src[z], a.dst[z], a.C[z]);
}

// ---- FUSED bt-GEMM batch (R9-proven): 128x128 tile, 832 blocks -> 2/CU
struct GemmDesc {
    const __bf16* A; const __bf16* B; const float* bias; __bf16* C;
    int lda, ldb, ldc, gx, nblocks, relu, biasrow; float scale;
};
struct FusedArgs { GemmDesc d[4]; };

__global__ __launch_bounds__(256, 2)
void gemm_fused(FusedArgs fa)
{
    __shared__ __align__(16) short As[2][128 * 64];
    __shared__ __align__(16) short Bs[2][128 * 64];

    int b = blockIdx.x, z = 0;
    while (b >= fa.d[z].nblocks) { b -= fa.d[z].nblocks; ++z; }
    const GemmDesc D = fa.d[z];
    const int m0 = (b % D.gx) * 128;
    const int n0 = (b / D.gx) * 128;

    const int tid  = threadIdx.x;
    const int lane = tid & 63;
    const int wv   = tid >> 6;
    const int c16  = lane & 15;
    const int quad = lane >> 4;
    const int swz  = c16 & 7;
    const int wr   = wv >> 1;
    const int wc   = wv & 1;

    f32x4 acc[4][4];
    #pragma unroll
    for (int i = 0; i < 4; ++i)
        #pragma unroll
        for (int j = 0; j < 4; ++j)
            acc[i][j] = (f32x4){0.f, 0.f, 0.f, 0.f};

    const int sRow = lane >> 3;
    const int sCh  = (lane & 7) ^ (sRow & 7);

    auto issue = [&](short* Abuf, short* Bbuf, int k0) {
        #pragma unroll
        for (int g = 0; g < 4; ++g) {
            int row = 32 * wv + 8 * g + sRow;
            const char* src = (const char*)(D.A + (size_t)(m0 + row) * D.lda + k0) + sCh * 16;
            gload_lds16(src, (char*)Abuf + (32 * wv + 8 * g) * 128);
        }
        #pragma unroll
        for (int g = 0; g < 4; ++g) {
            int row = 32 * wv + 8 * g + sRow;
            const char* src = (const char*)(D.B + (size_t)(n0 + row) * D.ldb + k0) + sCh * 16;
            gload_lds16(src, (char*)Bbuf + (32 * wv + 8 * g) * 128);
        }
    };
    auto compute = [&](const short* Abuf, const short* Bbuf) {
        __builtin_amdgcn_s_setprio(1);
        #pragma unroll
        for (int ks = 0; ks < 2; ++ks) {
            bf16x8 af[4], bfr[4];
            int slot = ((ks * 4 + quad) ^ swz) * 16;
            #pragma unroll
            for (int t = 0; t < 4; ++t)
                af[t] = *(const bf16x8*)((const char*)Abuf + (wr * 64 + t * 16 + c16) * 128 + slot);
            #pragma unroll
            for (int t = 0; t < 4; ++t)
                bfr[t] = *(const bf16x8*)((const char*)Bbuf + (wc * 64 + t * 16 + c16) * 128 + slot);
            #pragma unroll
            for (int tm = 0; tm < 4; ++tm)
                #pragma unroll
                for (int tn = 0; tn < 4; ++tn)
                    acc[tm][tn] = mfma16x16(af[tm], bfr[tn], acc[tm][tn]);
        }
        __builtin_amdgcn_s_setprio(0);
    };

    issue(As[0], Bs[0], 0);
    __syncthreads();

    #pragma unroll 1
    for (int t = 0; t < 16; t += 2) {
        if (t + 1 < 16) issue(As[1], Bs[1], (t + 1) << 6);
        compute(As[0], Bs[0]);
        __syncthreads();
        if (t + 2 < 16) issue(As[0], Bs[0], (t + 2) << 6);
        compute(As[1], Bs[1]);
        __syncthreads();
    }

    #pragma unroll
    for (int tm = 0; tm < 4; ++tm) {
        #pragma unroll
        for (int rr = 0; rr < 4; ++rr) {
            int row = m0 + wr * 64 + tm * 16 + quad * 4 + rr;
            float rbv = D.biasrow ? D.bias[row] : 0.0f;
            #pragma unroll
            for (int tn = 0; tn < 4; ++tn) {
                int col = n0 + wc * 64 + tn * 16 + c16;
                float bb = D.biasrow ? rbv : D.bias[col];
                float val = (acc[tm][tn][rr] + bb) * D.scale;
                if (D.relu) val = fmaxf(val, 0.0f);
                D.C[(size_t)row * D.ldc + col] = (__bf16)val;
            }
        }
    }
}

// ---- bt-GEMM 128x64 tile (R5-proven; 512 blocks = 2/CU) for out-projection
template<typename OutT, bool BIASROW>
__global__ __launch_bounds__(256, 2)
void gemm_bt64(const __bf16* __restrict__ A, int lda,
               const __bf16* __restrict__ B, int ldb,
               const float* __restrict__ bias,
               OutT* __restrict__ C, int ldc,
               float scale, int relu, const float* __restrict__ rowmask, int K)
{
    __shared__ __align__(16) short As[2][128 * 64];
    __shared__ __align__(16) short Bs[2][64 * 64];
    const int tid  = threadIdx.x;
    const int lane = tid & 63;
    const int wv   = tid >> 6;
    const int c16  = lane & 15;
    const int quad = lane >> 4;
    const int swz  = c16 & 7;
    const int wr   = wv >> 1;
    const int wc   = wv & 1;
    const int m0 = blockIdx.x * 128;
    const int n0 = blockIdx.y * 64;

    f32x4 acc[4][2];
    #pragma unroll
    for (int i = 0; i < 4; ++i)
        #pragma unroll
        for (int j = 0; j < 2; ++j)
            acc[i][j] = (f32x4){0.f, 0.f, 0.f, 0.f};

    const int sRow = lane >> 3;
    const int sCh  = (lane & 7) ^ (sRow & 7);

    auto issue = [&](short* Abuf, short* Bbuf, int k0) {
        #pragma unroll
        for (int g = 0; g < 4; ++g) {
            int row = 32 * wv + 8 * g + sRow;
            const char* src = (const char*)(A + (size_t)(m0 + row) * lda + k0) + sCh * 16;
            gload_lds16(src, (char*)Abuf + (32 * wv + 8 * g) * 128);
        }
        #pragma unroll
        for (int g = 0; g < 2; ++g) {
            int row = 16 * wv + 8 * g + sRow;
            const char* src = (const char*)(B + (size_t)(n0 + row) * ldb + k0) + sCh * 16;
            gload_lds16(src, (char*)Bbuf + (16 * wv + 8 * g) * 128);
        }
    };
    auto compute = [&](const short* Abuf, const short* Bbuf) {
        __builtin_amdgcn_s_setprio(1);
        #pragma unroll
        for (int ks = 0; ks < 2; ++ks) {
            bf16x8 af[4], bfr[2];
            int slot = ((ks * 4 + quad) ^ swz) * 16;
            #pragma unroll
            for (int t = 0; t < 4; ++t)
                af[t] = *(const bf16x8*)((const char*)Abuf + (wr * 64 + t * 16 + c16) * 128 + slot);
            #pragma unroll
            for (int t = 0; t < 2; ++t)
                bfr[t] = *(const bf16x8*)((const char*)Bbuf + (wc * 32 + t * 16 + c16) * 128 + slot);
            #pragma unroll
            for (int tm = 0; tm < 4; ++tm)
                #pragma unroll
                for (int tn = 0; tn < 2; ++tn)
                    acc[tm][tn] = mfma16x16(af[tm], bfr[tn], acc[tm][tn]);
        }
        __builtin_amdgcn_s_setprio(0);
    };

    const int nt = K >> 6;
    issue(As[0], Bs[0], 0);
    __syncthreads();

    #pragma unroll 1
    for (int t = 0; t < nt; t += 2) {
        if (t + 1 < nt) issue(As[1], Bs[1], (t + 1) << 6);
        compute(As[0], Bs[0]);
        __syncthreads();
        if (t + 1 < nt) {
            if (t + 2 < nt) issue(As[0], Bs[0], (t + 2) << 6);
            compute(As[1], Bs[1]);
            __syncthreads();
        }
    }

    #pragma unroll
    for (int tm = 0; tm < 4; ++tm) {
        #pragma unroll
        for (int rr = 0; rr < 4; ++rr) {
            int row = m0 + wr * 64 + tm * 16 + quad * 4 + rr;
            float mk = rowmask ? rowmask[row] : 1.0f;
            float rbv = BIASROW ? bias[row] : 0.0f;
            #pragma unroll
            for (int tn = 0; tn < 2; ++tn) {
                int col = n0 + wc * 32 + tn * 16 + c16;
                float b = BIASROW ? rbv : bias[col];
                float val = (acc[tm][tn][rr] + b) * scale;
                if (relu) val = fmaxf(val, 0.0f);
                val *= mk;
                C[(size_t)row * ldc + col] = (OutT)val;
            }
        }
    }
}

// ---- scores -> mask (unchanged)
__global__ void score_mask_kernel(const __bf16* __restrict__ h,
                                  const float* __restrict__ w2,
                                  const float* __restrict__ b2,
                                  float* __restrict__ maskf)
{
    int lane = threadIdx.x & 63;
    int tok  = blockIdx.x * 4 + (threadIdx.x >> 6);
    const __bf16* hr = h + (size_t)tok * 256;
    float s = 0.f;
    #pragma unroll
    for (int j = 0; j < 4; ++j) {
        int c = j * 64 + lane;
        s += (float)hr[c] * w2[c];
    }
    #pragma unroll
    for (int o = 1; o < 64; o <<= 1) s += __shfl_xor(s, o);
    if (lane == 0) {
        float x = s + b2[0];
        maskf[tok] = (x > -1.7346010553881064f) ? 1.0f : 0.0f;
    }
}

// ---- flash attention (R5/R9-proven structure): 16x16 MFMA, QBLK=128
// (8 waves x 16 q), K/V dbuf prefetch via gload_lds + XOR swizzle, fixed-max
// softmax, 2 k-splits, XCD-clustered grid 256.
// R13 delta: Ps rows padded 64 -> 72 shorts (144B): quad write stride
// 576B = 16 banks apart -> ~4-way instead of 8-way conflicts (R10-measured
// conflict halving, here without R10's register spill). LDS 146 KB.
__global__ __launch_bounds__(512, 1)
void attn_kernel(const __bf16* __restrict__ qp, const __bf16* __restrict__ kp,
                 const __bf16* __restrict__ vpT, const float* __restrict__ maskf,
                 __bf16* __restrict__ O0, __bf16* __restrict__ O1,
                 float* __restrict__ lbuf)
{
    __shared__ __align__(16) short Ks[2][64 * 256];    // 64 KB
    __shared__ __align__(16) short Vs[2][256 * 64];    // 64 KB
    __shared__ __align__(16) short PsA[8 * 16 * 72];   // 18 KB (padded)

    const int tid  = threadIdx.x;
    const int lane = tid & 63;
    const int wv   = tid >> 6;       // 0..7
    const int c16  = lane & 15;
    const int quad = lane >> 4;
    const int swz  = c16 & 7;

    const int d    = blockIdx.x;                 // 0..255, XCD = d & 7
    const int orig = ((d & 7) << 5) | (d >> 3);  // bijective: 8 groups x 32
    const int qb   = orig & 31;
    const int head = (orig >> 5) & 3;
    const int ksp  = orig >> 7;
    const int kbase = ksp * 2048;
    const int kend  = kbase + 2048;
    const int q0   = qb * 128 + wv * 16;
    short* Ps = PsA + wv * 16 * 72;
    __bf16* Ob = ksp ? O1 : O0;

    bf16x8 qf[8];
    #pragma unroll
    for (int c = 0; c < 8; ++c)
        qf[c] = *(const bf16x8*)(qp + (size_t)(q0 + c16) * DMODEL + head * DHEAD + c * 32 + quad * 8);

    f32x4 o[16];
    #pragma unroll
    for (int t = 0; t < 16; ++t) o[t] = (f32x4){0.f, 0.f, 0.f, 0.f};
    float psum[4] = {0.f, 0.f, 0.f, 0.f};

    const int kRow0 = wv * 8 + (lane >> 5);
    const int kCh   = lane & 31;
    const int vRow0 = wv * 32 + (lane >> 3);
    const int vCh   = (lane & 7) ^ ((lane >> 3) & 7);

    auto issue = [&](int buf, int n0) {
        #pragma unroll
        for (int g = 0; g < 4; ++g) {
            int key = kRow0 + g * 2;
            int c   = kCh ^ (key & 7);
            const char* src = (const char*)(kp + (size_t)(n0 + key) * DMODEL + head * DHEAD) + c * 16;
            gload_lds16(src, (char*)Ks[buf] + (wv * 8 + g * 2) * 512);
        }
        #pragma unroll
        for (int g = 0; g < 4; ++g) {
            int row = vRow0 + g * 8;
            const char* src = (const char*)(vpT + (size_t)(head * DHEAD + row) * N_TOK + n0) + vCh * 16;
            gload_lds16(src, (char*)Vs[buf] + (wv * 32 + g * 8) * 128);
        }
    };

    issue(0, kbase);
    __syncthreads();
    int cur = 0;

    #pragma unroll 1
    for (int n0 = kbase; n0 < kend; n0 += 64) {
        if (n0 + 64 < kend) issue(cur ^ 1, n0 + 64);
        const short* Kb = Ks[cur];
        const short* Vb = Vs[cur];

        f32x4 s[4];
        #pragma unroll
        for (int kt = 0; kt < 4; ++kt) s[kt] = (f32x4){0.f, 0.f, 0.f, 0.f};
        __builtin_amdgcn_s_setprio(1);
        #pragma unroll
        for (int c = 0; c < 8; ++c)
            #pragma unroll
            for (int kt = 0; kt < 4; ++kt) {
                bf16x8 bfr = *(const bf16x8*)(&Kb[(kt * 16 + c16) * 256 + (((c * 4 + quad) ^ swz) << 3)]);
                s[kt] = mfma16x16(qf[c], bfr, s[kt]);
            }
        __builtin_amdgcn_s_setprio(0);

        // p = exp(s + maskbias); per-lane denominator; store P (padded rows)
        #pragma unroll
        for (int kt = 0; kt < 4; ++kt) {
            float biasv = (maskf[n0 + kt * 16 + c16] - 1.0f) * 1e9f;
            #pragma unroll
            for (int r = 0; r < 4; ++r) {
                float p = __expf(s[kt][r] + biasv);
                psum[r] += p;
                *(__bf16*)&Ps[(quad * 4 + r) * 72 + kt * 16 + c16] = (__bf16)p;
            }
        }

        __builtin_amdgcn_s_waitcnt(0xc07f);  // lgkmcnt(0): own-wave Ps visible

        // O += P @ V
        __builtin_amdgcn_s_setprio(1);
        #pragma unroll
        for (int kstep = 0; kstep < 2; ++kstep) {
            bf16x8 pf = *(const bf16x8*)(&Ps[c16 * 72 + kstep * 32 + quad * 8]);
            #pragma unroll
            for (int t = 0; t < 16; ++t) {
                bf16x8 vf = *(const bf16x8*)(&Vb[(t * 16 + c16) * 64 + (((kstep * 4 + quad) ^ swz) << 3)]);
                o[t] = mfma16x16(pf, vf, o[t]);
            }
        }
        __builtin_amdgcn_s_setprio(0);
        __syncthreads();   // drains next-tile gloads (overlapped w/ compute)
        cur ^= 1;
    }

    float inv[4];
    #pragma unroll
    for (int r = 0; r < 4; ++r) {
        float t = psum[r];
        t += __shfl_xor(t, 1);
        t += __shfl_xor(t, 2);
        t += __shfl_xor(t, 4);
        t += __shfl_xor(t, 8);
        if (c16 == 0)
            lbuf[(size_t)(ksp * NHEAD + head) * N_TOK + q0 + quad * 4 + r] = t;
        inv[r] = 1.0f / t;
    }
    #pragma unroll
    for (int t = 0; t < 16; ++t)
        #pragma unroll
        for (int r = 0; r < 4; ++r) {
            float val = o[t][r] * inv[r];
            Ob[(size_t)(q0 + quad * 4 + r) * DMODEL + head * DHEAD + t * 16 + c16] = (__bf16)val;
        }
}

// ---- combine: ctx = (l0*O0 + l1*O1) / (l0+l1); exact (shared m=0)
__global__ void combine_kernel(const __bf16* __restrict__ O0,
                               const __bf16* __restrict__ O1,
                               const float* __restrict__ lbuf,
                               __bf16* __restrict__ out)
{
    int idx  = blockIdx.x * 256 + threadIdx.x;
    int tok  = idx >> 7;
    int g    = idx & 127;
    int head = g >> 5;
    float a = lbuf[(size_t)head * N_TOK + tok];
    float b = lbuf[(size_t)(NHEAD + head) * N_TOK + tok];
    float w0 = a / (a + b);
    float w1 = 1.0f - w0;
    size_t off = (size_t)tok * DMODEL + g * 8;
    bf16x8 x = *(const bf16x8*)(O0 + off);
    bf16x8 y = *(const bf16x8*)(O1 + off);
    bf16x8 z;
    #pragma unroll
    for (int j = 0; j < 8; ++j) z[j] = (__bf16)(w0 * (float)x[j] + w1 * (float)y[j]);
    *(bf16x8*)(out + off) = z;
}

extern "C" void kernel_launch(void* const* d_in, const int* in_sizes, int n_in,
                              void* d_out, int out_size, void* d_ws, size_t ws_size,
                              hipStream_t stream)
{
    (void)in_sizes; (void)n_in; (void)out_size;
    const float* q  = (const float*)d_in[0];
    const float* k  = (const float*)d_in[1];
    const float* v  = (const float*)d_in[2];
    const float* w1 = (const float*)d_in[3];
    const float* b1 = (const float*)d_in[4];
    const float* w2 = (const float*)d_in[5];
    const float* b2 = (const float*)d_in[6];
    const float* wq = (const float*)d_in[7];
    const float* bq = (const float*)d_in[8];
    const float* wk = (const float*)d_in[9];
    const float* bk = (const float*)d_in[10];
    const float* wvw = (const float*)d_in[11];
    const float* bv = (const float*)d_in[12];
    const float* wo = (const float*)d_in[13];
    const float* bo = (const float*)d_in[14];

    if (ws_size < 35667968u + 8388608u + 131072u) return;  // proven floor (R5)

    char* ws = (char*)d_ws;
    float*  maskf = (float*)ws;                       // 16 KB
    __bf16* hbuf  = (__bf16*)(ws + 16384);            // 2 MB; reused as woT after score_mask
    __bf16* qp    = (__bf16*)(ws + 16384 + 2097152);  // 8 MB each
    __bf16* kpb   = qp  + 4194304;
    __bf16* vpT   = kpb + 4194304;                    // [1024][4096] via swapped V-gemm
    __bf16* ctx   = vpT + 4194304;                    // O0; kbf scratch before attn
    __bf16* O1    = (__bf16*)(ws + 35667968u);        // 8 MB; qbf scratch before attn
    float*  lbuf  = (float*)(ws + 35667968u + 8388608u);

    // d_out (16 MB fp32) scratch, dead before final GEMM overwrites it:
    // wqT@0 | wkT@2M | wvT@4M | w1T@6M | vbf@6.5M..14.5M
    __bf16* wqT = (__bf16*)d_out;
    __bf16* wkT = wqT + 1048576;
    __bf16* wvT = wkT + 1048576;
    __bf16* w1T = wvT + 1048576;
    __bf16* vbf = (__bf16*)((char*)d_out + 6815744u);
    __bf16* woT = hbuf;                               // reuses hbuf after score_mask
    __bf16* qbf = O1;                                 // dead until attn writes O1
    __bf16* kbf = ctx;                                // dead until attn writes O0

    // 0) q,k,v -> bf16 (one launch)
    CvtArgs ca;
    ca.src[0] = q;  ca.dst[0] = qbf;
    ca.src[1] = k;  ca.dst[1] = kbf;
    ca.src[2] = v;  ca.dst[2] = vbf;
    cvt_bf16_kernel<<<dim3(2048, 3), 256, 0, stream>>>(ca);

    // 1) transpose w1,wq,wk,wv (one launch)
    TWArgs ta;
    ta.src[0] = w1;  ta.dst[0] = w1T;  ta.C[0] = 256;
    ta.src[1] = wq;  ta.dst[1] = wqT;  ta.C[1] = 1024;
    ta.src[2] = wk;  ta.dst[2] = wkT;  ta.C[2] = 1024;
    ta.src[3] = wvw; ta.dst[3] = wvT;  ta.C[3] = 1024;
    transposew_batch_kernel<<<dim3(16, 16, 4), 256, 0, stream>>>(ta);

    // 2) FUSED: h = relu(q@w1+b1) | qp = (q@wq)/16 | kp = k@wk | vpT = (v@wv)^T
    FusedArgs fa;
    fa.d[0] = { qbf, w1T, b1, hbuf, 1024, 1024,  256, 32,  64, 1, 0, 1.0f };
    fa.d[1] = { qbf, wqT, bq, qp,   1024, 1024, 1024, 32, 256, 0, 0, 0.0625f };
    fa.d[2] = { kbf, wkT, bk, kpb,  1024, 1024, 1024, 32, 256, 0, 0, 1.0f };
    fa.d[3] = { wvT, vbf, bv, vpT,  1024, 1024, 4096,  8, 256, 0, 1, 1.0f };
    gemm_fused<<<dim3(832), 256, 0, stream>>>(fa);

    // 3) mask, then wo^T into hbuf (hbuf free after score_mask)
    score_mask_kernel<<<1024, 256, 0, stream>>>(hbuf, w2, b2, maskf);
    transposew_kernel<<<dim3(16, 16), 256, 0, stream>>>(wo, woT, 1024);

    // 4) attention (256 blocks, 512 thr, dbuf prefetch, XCD-clustered)
    attn_kernel<<<dim3(256), 512, 0, stream>>>(qp, kpb, vpT, maskf, ctx, O1, lbuf);
    combine_kernel<<<2048, 256, 0, stream>>>(ctx, O1, lbuf, ctx);

    // 5) out-projection (128x64 tile, 512 blocks = 2/CU)
    gemm_bt64<float, false><<<dim3(32, 16), 256, 0, stream>>>(
        ctx, 1024, woT, 1024, bo, (float*)d_out, 1024, 1.0f, 0, maskf, 1024);
}

// Round 14
// 300.191 us; speedup vs baseline: 1.2490x; 1.0197x over previous
//
#include <hip/hip_runtime.h>
#include <hip/hip_bf16.h>
#include <math.h>

typedef __bf16 bf16x8 __attribute__((ext_vector_type(8)));
typedef __bf16 bf16x4 __attribute__((ext_vector_type(4)));
typedef float  f32x4  __attribute__((ext_vector_type(4)));
typedef short  s16x8  __attribute__((ext_vector_type(8)));

#define N_TOK  4096
#define DMODEL 1024
#define NHEAD  4
#define DHEAD  256

__device__ __forceinline__ f32x4 mfma16x16(bf16x8 a, bf16x8 b, f32x4 c) {
    return __builtin_amdgcn_mfma_f32_16x16x32_bf16(a, b, c, 0, 0, 0);
}

// async global->LDS, 16B per lane; LDS dest = wave-uniform base + lane*16
__device__ __forceinline__ void gload_lds16(const void* gsrc, void* ldst) {
    __builtin_amdgcn_global_load_lds(
        (const __attribute__((address_space(1))) void*)gsrc,
        (__attribute__((address_space(3))) void*)ldst, 16, 0, 0);
}

// ---- batched fp32 -> bf16 convert (q,k,v), 8 elem/thread
struct CvtArgs { const float* src[3]; __bf16* dst[3]; };
__global__ __launch_bounds__(256)
void cvt_bf16_kernel(CvtArgs a)
{
    const float* in = a.src[blockIdx.y];
    __bf16* out = a.dst[blockIdx.y];
    size_t i8 = ((size_t)blockIdx.x * 256 + threadIdx.x) * 8;
    f32x4 t0 = *(const f32x4*)(in + i8);
    f32x4 t1 = *(const f32x4*)(in + i8 + 4);
    bf16x8 b;
    #pragma unroll
    for (int j = 0; j < 4; ++j) { b[j] = (__bf16)t0[j]; b[j + 4] = (__bf16)t1[j]; }
    *(bf16x8*)(out + i8) = b;
}

// ---- weight transpose+convert: in [1024][C] fp32 -> out [C][1024] bf16
__device__ __forceinline__ void transposew_body(const float* __restrict__ in,
                                                __bf16* __restrict__ out, int C)
{
    __shared__ __align__(16) __bf16 tile[64 * 72];
    const int tid = threadIdx.x;
    const int r0 = blockIdx.x * 64;
    const int c0 = blockIdx.y * 64;
    if (c0 >= C) return;
    #pragma unroll
    for (int it = 0; it < 4; ++it) {
        int i = tid + it * 256;
        int row = i >> 4, c4 = i & 15;
        f32x4 v = *(const f32x4*)(in + (size_t)(r0 + row) * C + c0 + c4 * 4);
        #pragma unroll
        for (int j = 0; j < 4; ++j)
            tile[(c4 * 4 + j) * 72 + row] = (__bf16)v[j];
    }
    __syncthreads();
    #pragma unroll
    for (int it = 0; it < 2; ++it) {
        int i = tid + it * 256;
        int col = i >> 3, ch = i & 7;
        s16x8 v = *(const s16x8*)(&tile[col * 72 + ch * 8]);
        *(s16x8*)((short*)out + (size_t)(c0 + col) * 1024 + r0 + ch * 8) = v;
    }
}

__global__ __launch_bounds__(256)
void transposew_kernel(const float* __restrict__ in, __bf16* __restrict__ out, int C)
{
    transposew_body(in, out, C);
}

struct TWArgs { const float* src[4]; __bf16* dst[4]; int C[4]; };
__global__ __launch_bounds__(256)
void transposew_batch_kernel(TWArgs a)
{
    int z = blockIdx.z;
    transposew_body(a.src[z], a.dst[z], a.C[z]);
}

// ---- FUSED bt-GEMM batch, XCD-CLUSTERED (T1): 128x128 tile, 832 blocks.
// XCD = blockIdx & 7 (R3-verified: attn FETCH 69.7->16.5MB with this map).
// Each XCD's L2 (4MB) holds one operand-slice pair:
//   h/qp/kp (B<=2MB): XCD x owns m-rows [4x,4x+4) x all n  (A-slice 1MB + B)
//   vpT     (A=2MB):  XCD x owns n-cols [4x,4x+4) x all m  (B-slice 1MB + A)
struct GemmDesc {
    const __bf16* A; const __bf16* B; const float* bias; __bf16* C;
    int lda, ldb, ldc, relu, biasrow; float scale;
};
struct FusedArgs { GemmDesc d[4]; };

__global__ __launch_bounds__(256, 2)
void gemm_fused(FusedArgs fa)
{
    __shared__ __align__(16) short As[2][128 * 64];
    __shared__ __align__(16) short Bs[2][128 * 64];

    // XCD-clustered decode: xcd = d&7, slot = d>>3 (0..103)
    const int dd  = blockIdx.x;
    const int xcd = dd & 7;
    const int slot = dd >> 3;
    int z, mIdx, nIdx;
    if (slot < 8) {                 // h: 32m x 2n, m-slice
        z = 0; int s = slot;
        mIdx = xcd * 4 + (s >> 1); nIdx = s & 1;
    } else if (slot < 40) {         // qp: 32m x 8n, m-slice
        z = 1; int s = slot - 8;
        mIdx = xcd * 4 + (s >> 3); nIdx = s & 7;
    } else if (slot < 72) {         // kp: 32m x 8n, m-slice
        z = 2; int s = slot - 40;
        mIdx = xcd * 4 + (s >> 3); nIdx = s & 7;
    } else {                        // vpT: 8m x 32n, n-slice
        z = 3; int s = slot - 72;
        nIdx = xcd * 4 + (s >> 3); mIdx = s & 7;
    }
    const GemmDesc D = fa.d[z];
    const int m0 = mIdx * 128;
    const int n0 = nIdx * 128;

    const int tid  = threadIdx.x;
    const int lane = tid & 63;
    const int wv   = tid >> 6;
    const int c16  = lane & 15;
    const int quad = lane >> 4;
    const int swz  = c16 & 7;
    const int wr   = wv >> 1;
    const int wc   = wv & 1;

    f32x4 acc[4][4];
    #pragma unroll
    for (int i = 0; i < 4; ++i)
        #pragma unroll
        for (int j = 0; j < 4; ++j)
            acc[i][j] = (f32x4){0.f, 0.f, 0.f, 0.f};

    const int sRow = lane >> 3;
    const int sCh  = (lane & 7) ^ (sRow & 7);

    auto issue = [&](short* Abuf, short* Bbuf, int k0) {
        #pragma unroll
        for (int g = 0; g < 4; ++g) {
            int row = 32 * wv + 8 * g + sRow;
            const char* src = (const char*)(D.A + (size_t)(m0 + row) * D.lda + k0) + sCh * 16;
            gload_lds16(src, (char*)Abuf + (32 * wv + 8 * g) * 128);
        }
        #pragma unroll
        for (int g = 0; g < 4; ++g) {
            int row = 32 * wv + 8 * g + sRow;
            const char* src = (const char*)(D.B + (size_t)(n0 + row) * D.ldb + k0) + sCh * 16;
            gload_lds16(src, (char*)Bbuf + (32 * wv + 8 * g) * 128);
        }
    };
    auto compute = [&](const short* Abuf, const short* Bbuf) {
        __builtin_amdgcn_s_setprio(1);
        #pragma unroll
        for (int ks = 0; ks < 2; ++ks) {
            bf16x8 af[4], bfr[4];
            int slot2 = ((ks * 4 + quad) ^ swz) * 16;
            #pragma unroll
            for (int t = 0; t < 4; ++t)
                af[t] = *(const bf16x8*)((const char*)Abuf + (wr * 64 + t * 16 + c16) * 128 + slot2);
            #pragma unroll
            for (int t = 0; t < 4; ++t)
                bfr[t] = *(const bf16x8*)((const char*)Bbuf + (wc * 64 + t * 16 + c16) * 128 + slot2);
            #pragma unroll
            for (int tm = 0; tm < 4; ++tm)
                #pragma unroll
                for (int tn = 0; tn < 4; ++tn)
                    acc[tm][tn] = mfma16x16(af[tm], bfr[tn], acc[tm][tn]);
        }
        __builtin_amdgcn_s_setprio(0);
    };

    issue(As[0], Bs[0], 0);
    __syncthreads();

    #pragma unroll 1
    for (int t = 0; t < 16; t += 2) {
        if (t + 1 < 16) issue(As[1], Bs[1], (t + 1) << 6);
        compute(As[0], Bs[0]);
        __syncthreads();
        if (t + 2 < 16) issue(As[0], Bs[0], (t + 2) << 6);
        compute(As[1], Bs[1]);
        __syncthreads();
    }

    #pragma unroll
    for (int tm = 0; tm < 4; ++tm) {
        #pragma unroll
        for (int rr = 0; rr < 4; ++rr) {
            int row = m0 + wr * 64 + tm * 16 + quad * 4 + rr;
            float rbv = D.biasrow ? D.bias[row] : 0.0f;
            #pragma unroll
            for (int tn = 0; tn < 4; ++tn) {
                int col = n0 + wc * 64 + tn * 16 + c16;
                float bb = D.biasrow ? rbv : D.bias[col];
                float val = (acc[tm][tn][rr] + bb) * D.scale;
                if (D.relu) val = fmaxf(val, 0.0f);
                D.C[(size_t)row * D.ldc + col] = (__bf16)val;
            }
        }
    }
}

// ---- out-projection GEMM: 128x64 tile, 512 blocks flat, XCD-clustered
// (XCD x owns m-rows [4x,4x+4) x all 16 n-cols: A-slice 1MB + woT 2MB in L2).
template<typename OutT>
__global__ __launch_bounds__(256, 2)
void gemm_out(const __bf16* __restrict__ A, int lda,
              const __bf16* __restrict__ B, int ldb,
              const float* __restrict__ bias,
              OutT* __restrict__ C, int ldc,
              float scale, const float* __restrict__ rowmask, int K)
{
    __shared__ __align__(16) short As[2][128 * 64];
    __shared__ __align__(16) short Bs[2][64 * 64];
    const int dd  = blockIdx.x;             // 0..511
    const int xcd = dd & 7;
    const int s   = dd >> 3;                // 0..63
    const int m0  = (xcd * 4 + (s >> 4)) * 128;   // m-block 0..31
    const int n0  = (s & 15) * 64;                // n-block 0..15

    const int tid  = threadIdx.x;
    const int lane = tid & 63;
    const int wv   = tid >> 6;
    const int c16  = lane & 15;
    const int quad = lane >> 4;
    const int swz  = c16 & 7;
    const int wr   = wv >> 1;
    const int wc   = wv & 1;

    f32x4 acc[4][2];
    #pragma unroll
    for (int i = 0; i < 4; ++i)
        #pragma unroll
        for (int j = 0; j < 2; ++j)
            acc[i][j] = (f32x4){0.f, 0.f, 0.f, 0.f};

    const int sRow = lane >> 3;
    const int sCh  = (lane & 7) ^ (sRow & 7);

    auto issue = [&](short* Abuf, short* Bbuf, int k0) {
        #pragma unroll
        for (int g = 0; g < 4; ++g) {
            int row = 32 * wv + 8 * g + sRow;
            const char* src = (const char*)(A + (size_t)(m0 + row) * lda + k0) + sCh * 16;
            gload_lds16(src, (char*)Abuf + (32 * wv + 8 * g) * 128);
        }
        #pragma unroll
        for (int g = 0; g < 2; ++g) {
            int row = 16 * wv + 8 * g + sRow;
            const char* src = (const char*)(B + (size_t)(n0 + row) * ldb + k0) + sCh * 16;
            gload_lds16(src, (char*)Bbuf + (16 * wv + 8 * g) * 128);
        }
    };
    auto compute = [&](const short* Abuf, const short* Bbuf) {
        __builtin_amdgcn_s_setprio(1);
        #pragma unroll
        for (int ks = 0; ks < 2; ++ks) {
            bf16x8 af[4], bfr[2];
            int slot = ((ks * 4 + quad) ^ swz) * 16;
            #pragma unroll
            for (int t = 0; t < 4; ++t)
                af[t] = *(const bf16x8*)((const char*)Abuf + (wr * 64 + t * 16 + c16) * 128 + slot);
            #pragma unroll
            for (int t = 0; t < 2; ++t)
                bfr[t] = *(const bf16x8*)((const char*)Bbuf + (wc * 32 + t * 16 + c16) * 128 + slot);
            #pragma unroll
            for (int tm = 0; tm < 4; ++tm)
                #pragma unroll
                for (int tn = 0; tn < 2; ++tn)
                    acc[tm][tn] = mfma16x16(af[tm], bfr[tn], acc[tm][tn]);
        }
        __builtin_amdgcn_s_setprio(0);
    };

    const int nt = K >> 6;
    issue(As[0], Bs[0], 0);
    __syncthreads();

    #pragma unroll 1
    for (int t = 0; t < nt; t += 2) {
        if (t + 1 < nt) issue(As[1], Bs[1], (t + 1) << 6);
        compute(As[0], Bs[0]);
        __syncthreads();
        if (t + 1 < nt) {
            if (t + 2 < nt) issue(As[0], Bs[0], (t + 2) << 6);
            compute(As[1], Bs[1]);
            __syncthreads();
        }
    }

    #pragma unroll
    for (int tm = 0; tm < 4; ++tm) {
        #pragma unroll
        for (int rr = 0; rr < 4; ++rr) {
            int row = m0 + wr * 64 + tm * 16 + quad * 4 + rr;
            float mk = rowmask ? rowmask[row] : 1.0f;
            #pragma unroll
            for (int tn = 0; tn < 2; ++tn) {
                int col = n0 + wc * 32 + tn * 16 + c16;
                float val = (acc[tm][tn][rr] + bias[col]) * scale;
                val *= mk;
                C[(size_t)row * ldc + col] = (OutT)val;
            }
        }
    }
}

// ---- scores -> mask (unchanged)
__global__ void score_mask_kernel(const __bf16* __restrict__ h,
                                  const float* __restrict__ w2,
                                  const float* __restrict__ b2,
                                  float* __restrict__ maskf)
{
    int lane = threadIdx.x & 63;
    int tok  = blockIdx.x * 4 + (threadIdx.x >> 6);
    const __bf16* hr = h + (size_t)tok * 256;
    float s = 0.f;
    #pragma unroll
    for (int j = 0; j < 4; ++j) {
        int c = j * 64 + lane;
        s += (float)hr[c] * w2[c];
    }
    #pragma unroll
    for (int o = 1; o < 64; o <<= 1) s += __shfl_xor(s, o);
    if (lane == 0) {
        float x = s + b2[0];
        maskf[tok] = (x > -1.7346010553881064f) ? 1.0f : 0.0f;
    }
}

// ---- flash attention (R13-proven, unchanged)
__global__ __launch_bounds__(512, 1)
void attn_kernel(const __bf16* __restrict__ qp, const __bf16* __restrict__ kp,
                 const __bf16* __restrict__ vpT, const float* __restrict__ maskf,
                 __bf16* __restrict__ O0, __bf16* __restrict__ O1,
                 float* __restrict__ lbuf)
{
    __shared__ __align__(16) short Ks[2][64 * 256];    // 64 KB
    __shared__ __align__(16) short Vs[2][256 * 64];    // 64 KB
    __shared__ __align__(16) short PsA[8 * 16 * 72];   // 18 KB (padded)

    const int tid  = threadIdx.x;
    const int lane = tid & 63;
    const int wv   = tid >> 6;       // 0..7
    const int c16  = lane & 15;
    const int quad = lane >> 4;
    const int swz  = c16 & 7;

    const int d    = blockIdx.x;                 // 0..255, XCD = d & 7
    const int orig = ((d & 7) << 5) | (d >> 3);  // bijective: 8 groups x 32
    const int qb   = orig & 31;
    const int head = (orig >> 5) & 3;
    const int ksp  = orig >> 7;
    const int kbase = ksp * 2048;
    const int kend  = kbase + 2048;
    const int q0   = qb * 128 + wv * 16;
    short* Ps = PsA + wv * 16 * 72;
    __bf16* Ob = ksp ? O1 : O0;

    bf16x8 qf[8];
    #pragma unroll
    for (int c = 0; c < 8; ++c)
        qf[c] = *(const bf16x8*)(qp + (size_t)(q0 + c16) * DMODEL + head * DHEAD + c * 32 + quad * 8);

    f32x4 o[16];
    #pragma unroll
    for (int t = 0; t < 16; ++t) o[t] = (f32x4){0.f, 0.f, 0.f, 0.f};
    float psum[4] = {0.f, 0.f, 0.f, 0.f};

    const int kRow0 = wv * 8 + (lane >> 5);
    const int kCh   = lane & 31;
    const int vRow0 = wv * 32 + (lane >> 3);
    const int vCh   = (lane & 7) ^ ((lane >> 3) & 7);

    auto issue = [&](int buf, int n0) {
        #pragma unroll
        for (int g = 0; g < 4; ++g) {
            int key = kRow0 + g * 2;
            int c   = kCh ^ (key & 7);
            const char* src = (const char*)(kp + (size_t)(n0 + key) * DMODEL + head * DHEAD) + c * 16;
            gload_lds16(src, (char*)Ks[buf] + (wv * 8 + g * 2) * 512);
        }
        #pragma unroll
        for (int g = 0; g < 4; ++g) {
            int row = vRow0 + g * 8;
            const char* src = (const char*)(vpT + (size_t)(head * DHEAD + row) * N_TOK + n0) + vCh * 16;
            gload_lds16(src, (char*)Vs[buf] + (wv * 32 + g * 8) * 128);
        }
    };

    issue(0, kbase);
    __syncthreads();
    int cur = 0;

    #pragma unroll 1
    for (int n0 = kbase; n0 < kend; n0 += 64) {
        if (n0 + 64 < kend) issue(cur ^ 1, n0 + 64);
        const short* Kb = Ks[cur];
        const short* Vb = Vs[cur];

        f32x4 s[4];
        #pragma unroll
        for (int kt = 0; kt < 4; ++kt) s[kt] = (f32x4){0.f, 0.f, 0.f, 0.f};
        __builtin_amdgcn_s_setprio(1);
        #pragma unroll
        for (int c = 0; c < 8; ++c)
            #pragma unroll
            for (int kt = 0; kt < 4; ++kt) {
                bf16x8 bfr = *(const bf16x8*)(&Kb[(kt * 16 + c16) * 256 + (((c * 4 + quad) ^ swz) << 3)]);
                s[kt] = mfma16x16(qf[c], bfr, s[kt]);
            }
        __builtin_amdgcn_s_setprio(0);

        #pragma unroll
        for (int kt = 0; kt < 4; ++kt) {
            float biasv = (maskf[n0 + kt * 16 + c16] - 1.0f) * 1e9f;
            #pragma unroll
            for (int r = 0; r < 4; ++r) {
                float p = __expf(s[kt][r] + biasv);
                psum[r] += p;
                *(__bf16*)&Ps[(quad * 4 + r) * 72 + kt * 16 + c16] = (__bf16)p;
            }
        }

        __builtin_amdgcn_s_waitcnt(0xc07f);  // lgkmcnt(0): own-wave Ps visible

        __builtin_amdgcn_s_setprio(1);
        #pragma unroll
        for (int kstep = 0; kstep < 2; ++kstep) {
            bf16x8 pf = *(const bf16x8*)(&Ps[c16 * 72 + kstep * 32 + quad * 8]);
            #pragma unroll
            for (int t = 0; t < 16; ++t) {
                bf16x8 vf = *(const bf16x8*)(&Vb[(t * 16 + c16) * 64 + (((kstep * 4 + quad) ^ swz) << 3)]);
                o[t] = mfma16x16(pf, vf, o[t]);
            }
        }
        __builtin_amdgcn_s_setprio(0);
        __syncthreads();
        cur ^= 1;
    }

    float inv[4];
    #pragma unroll
    for (int r = 0; r < 4; ++r) {
        float t = psum[r];
        t += __shfl_xor(t, 1);
        t += __shfl_xor(t, 2);
        t += __shfl_xor(t, 4);
        t += __shfl_xor(t, 8);
        if (c16 == 0)
            lbuf[(size_t)(ksp * NHEAD + head) * N_TOK + q0 + quad * 4 + r] = t;
        inv[r] = 1.0f / t;
    }
    #pragma unroll
    for (int t = 0; t < 16; ++t)
        #pragma unroll
        for (int r = 0; r < 4; ++r) {
            float val = o[t][r] * inv[r];
            Ob[(size_t)(q0 + quad * 4 + r) * DMODEL + head * DHEAD + t * 16 + c16] = (__bf16)val;
        }
}

// ---- combine (unchanged)
__global__ void combine_kernel(const __bf16* __restrict__ O0,
                               const __bf16* __restrict__ O1,
                               const float* __restrict__ lbuf,
                               __bf16* __restrict__ out)
{
    int idx  = blockIdx.x * 256 + threadIdx.x;
    int tok  = idx >> 7;
    int g    = idx & 127;
    int head = g >> 5;
    float a = lbuf[(size_t)head * N_TOK + tok];
    float b = lbuf[(size_t)(NHEAD + head) * N_TOK + tok];
    float w0 = a / (a + b);
    float w1 = 1.0f - w0;
    size_t off = (size_t)tok * DMODEL + g * 8;
    bf16x8 x = *(const bf16x8*)(O0 + off);
    bf16x8 y = *(const bf16x8*)(O1 + off);
    bf16x8 z;
    #pragma unroll
    for (int j = 0; j < 8; ++j) z[j] = (__bf16)(w0 * (float)x[j] + w1 * (float)y[j]);
    *(bf16x8*)(out + off) = z;
}

extern "C" void kernel_launch(void* const* d_in, const int* in_sizes, int n_in,
                              void* d_out, int out_size, void* d_ws, size_t ws_size,
                              hipStream_t stream)
{
    (void)in_sizes; (void)n_in; (void)out_size;
    const float* q  = (const float*)d_in[0];
    const float* k  = (const float*)d_in[1];
    const float* v  = (const float*)d_in[2];
    const float* w1 = (const float*)d_in[3];
    const float* b1 = (const float*)d_in[4];
    const float* w2 = (const float*)d_in[5];
    const float* b2 = (const float*)d_in[6];
    const float* wq = (const float*)d_in[7];
    const float* bq = (const float*)d_in[8];
    const float* wk = (const float*)d_in[9];
    const float* bk = (const float*)d_in[10];
    const float* wvw = (const float*)d_in[11];
    const float* bv = (const float*)d_in[12];
    const float* wo = (const float*)d_in[13];
    const float* bo = (const float*)d_in[14];

    if (ws_size < 35667968u + 8388608u + 131072u) return;  // proven floor (R5)

    char* ws = (char*)d_ws;
    float*  maskf = (float*)ws;                       // 16 KB
    __bf16* hbuf  = (__bf16*)(ws + 16384);            // 2 MB; reused as woT after score_mask
    __bf16* qp    = (__bf16*)(ws + 16384 + 2097152);  // 8 MB each
    __bf16* kpb   = qp  + 4194304;
    __bf16* vpT   = kpb + 4194304;                    // [1024][4096] via swapped V-gemm
    __bf16* ctx   = vpT + 4194304;                    // O0; kbf scratch before attn
    __bf16* O1    = (__bf16*)(ws + 35667968u);        // 8 MB; qbf scratch before attn
    float*  lbuf  = (float*)(ws + 35667968u + 8388608u);

    // d_out (16 MB fp32) scratch, dead before final GEMM overwrites it:
    // wqT@0 | wkT@2M | wvT@4M | w1T@6M | vbf@6.5M..14.5M
    __bf16* wqT = (__bf16*)d_out;
    __bf16* wkT = wqT + 1048576;
    __bf16* wvT = wkT + 1048576;
    __bf16* w1T = wvT + 1048576;
    __bf16* vbf = (__bf16*)((char*)d_out + 6815744u);
    __bf16* woT = hbuf;                               // reuses hbuf after score_mask
    __bf16* qbf = O1;                                 // dead until attn writes O1
    __bf16* kbf = ctx;                                // dead until attn writes O0

    // 0) q,k,v -> bf16 (one launch)
    CvtArgs ca;
    ca.src[0] = q;  ca.dst[0] = qbf;
    ca.src[1] = k;  ca.dst[1] = kbf;
    ca.src[2] = v;  ca.dst[2] = vbf;
    cvt_bf16_kernel<<<dim3(2048, 3), 256, 0, stream>>>(ca);

    // 1) transpose w1,wq,wk,wv (one launch)
    TWArgs ta;
    ta.src[0] = w1;  ta.dst[0] = w1T;  ta.C[0] = 256;
    ta.src[1] = wq;  ta.dst[1] = wqT;  ta.C[1] = 1024;
    ta.src[2] = wk;  ta.dst[2] = wkT;  ta.C[2] = 1024;
    ta.src[3] = wvw; ta.dst[3] = wvT;  ta.C[3] = 1024;
    transposew_batch_kernel<<<dim3(16, 16, 4), 256, 0, stream>>>(ta);

    // 2) FUSED (XCD-clustered): h | qp | kp | vpT
    FusedArgs fa;
    fa.d[0] = { qbf, w1T, b1, hbuf, 1024, 1024,  256, 1, 0, 1.0f };
    fa.d[1] = { qbf, wqT, bq, qp,   1024, 1024, 1024, 0, 0, 0.0625f };
    fa.d[2] = { kbf, wkT, bk, kpb,  1024, 1024, 1024, 0, 0, 1.0f };
    fa.d[3] = { wvT, vbf, bv, vpT,  1024, 1024, 4096, 0, 1, 1.0f };
    gemm_fused<<<dim3(832), 256, 0, stream>>>(fa);

    // 3) mask, then wo^T into hbuf (hbuf free after score_mask)
    score_mask_kernel<<<1024, 256, 0, stream>>>(hbuf, w2, b2, maskf);
    transposew_kernel<<<dim3(16, 16), 256, 0, stream>>>(wo, woT, 1024);

    // 4) attention (256 blocks, 512 thr, dbuf prefetch, XCD-clustered)
    attn_kernel<<<dim3(256), 512, 0, stream>>>(qp, kpb, vpT, maskf, ctx, O1, lbuf);
    combine_kernel<<<2048, 256, 0, stream>>>(ctx, O1, lbuf, ctx);

    // 5) out-projection (128x64 tile, 512 blocks flat, XCD-clustered)
    gemm_out<float><<<dim3(512), 256, 0, stream>>>(
        ctx, 1024, woT, 1024, bo, (float*)d_out, 1024, 1.0f, maskf, 1024);
}